// Round 2
// baseline (457.578 us; speedup 1.0000x reference)
//
#include <hip/hip_runtime.h>

// AdaptiveMemory: out[b,:] = cm(b)*mem[vids[b],:] + ch(b)*h_last[b,:]
//   alpha = sigmoid(dot(h_last[b,:], W_alpha) + b_alpha)
//   cm = d + (1-d)*alpha ; ch = (1-d)*(1-alpha)
// B=4096, D=1024. One block per row, 256 threads, float4 per thread.

#define D_DIM 1024
#define BLOCK 256   // D_DIM / 4 floats per thread

__global__ __launch_bounds__(BLOCK) void AdaptiveMemory_kernel(
    const float* __restrict__ h_last,   // [B, D]
    const int*   __restrict__ vids,     // [B]
    const float* __restrict__ mem,      // [N_VIDEOS, D]
    const float* __restrict__ W_alpha,  // [D, 1]
    const float* __restrict__ b_alpha,  // [1]
    const float* __restrict__ decay_p,  // [1]
    float*       __restrict__ out)      // [B, D]
{
    const int row = blockIdx.x;
    const int tid = threadIdx.x;

    const float4* __restrict__ h4 =
        (const float4*)(h_last + (size_t)row * D_DIM);
    const float4* __restrict__ w4 = (const float4*)W_alpha;

    // Load h fragment once; reused for dot and for the fused update.
    float4 h = h4[tid];
    float4 w = w4[tid];

    float partial = h.x * w.x + h.y * w.y + h.z * w.z + h.w * w.w;

    // Wave-64 shuffle reduction
    #pragma unroll
    for (int off = 32; off > 0; off >>= 1)
        partial += __shfl_down(partial, off, 64);

    __shared__ float wave_sums[BLOCK / 64];
    __shared__ float alpha_sh;
    const int wave = tid >> 6;
    if ((tid & 63) == 0) wave_sums[wave] = partial;
    __syncthreads();

    if (tid == 0) {
        float dot = wave_sums[0] + wave_sums[1] + wave_sums[2] + wave_sums[3]
                  + b_alpha[0];
        alpha_sh = 1.0f / (1.0f + expf(-dot));
    }
    __syncthreads();

    const float alpha = alpha_sh;
    const float d     = decay_p[0];
    const float cm    = d + (1.0f - d) * alpha;          // coeff on M
    const float ch    = (1.0f - d) * (1.0f - alpha);     // coeff on h

    const int vid = vids[row];
    const float4* __restrict__ m4 =
        (const float4*)(mem + (size_t)vid * D_DIM);
    float4 m = m4[tid];

    float4 o;
    o.x = cm * m.x + ch * h.x;
    o.y = cm * m.y + ch * h.y;
    o.z = cm * m.z + ch * h.z;
    o.w = cm * m.w + ch * h.w;

    ((float4*)(out + (size_t)row * D_DIM))[tid] = o;
}

extern "C" void kernel_launch(void* const* d_in, const int* in_sizes, int n_in,
                              void* d_out, int out_size, void* d_ws, size_t ws_size,
                              hipStream_t stream) {
    const float* h_last  = (const float*)d_in[0];
    const int*   vids    = (const int*)d_in[1];
    const float* mem     = (const float*)d_in[2];
    const float* W_alpha = (const float*)d_in[3];
    const float* b_alpha = (const float*)d_in[4];
    const float* decay   = (const float*)d_in[5];
    float* out = (float*)d_out;

    const int B = in_sizes[1];  // number of rows (vids has B elements)

    AdaptiveMemory_kernel<<<B, BLOCK, 0, stream>>>(
        h_last, vids, mem, W_alpha, b_alpha, decay, out);
}